// Round 7
// baseline (125.346 us; speedup 1.0000x reference)
//
#include <hip/hip_runtime.h>
#include <hip/hip_bf16.h>
#include <stdint.h>

typedef __bf16 bf16x8 __attribute__((ext_vector_type(8)));
typedef float f32x4 __attribute__((ext_vector_type(4)));

constexpr int Bn = 8, Ln = 4096, Dn = 512, Hn = 512;
constexpr int Mrows = Bn * Ln;                  // 32768
constexpr int CHUNK = 64, NCHUNK = Ln / CHUNK;  // 64 chunks of 64
constexpr int LNBLK = Mrows / 4;                // 8192: 1 row per wave, 4 waves/block

// ---------------------------------------------------------------- pre: LN (wave-per-row) + weight prep
// LN row mapping XCD-aligned: blk%8 = batch, so XN[batch b] is produced on
// XCD b — the same XCD whose GEMM1 blocks read it (bid%8=x -> rows 4096x..).
__global__ __launch_bounds__(256) void pre_kernel(
    const float* __restrict__ x, const float* __restrict__ gamma,
    const float* __restrict__ beta,
    const float* __restrict__ W_B, const float* __restrict__ W_C,
    const float* __restrict__ W_out, const float* __restrict__ b_B,
    const float* __restrict__ b_C,
    __hip_bfloat16* __restrict__ xn,
    __hip_bfloat16* __restrict__ WbcT, __hip_bfloat16* __restrict__ WoT,
    float* __restrict__ bbc)
{
    int t = threadIdx.x;
    if (blockIdx.x >= LNBLK) {                 // prep role: 2048 blocks
        int id = (blockIdx.x - LNBLK) * 256 + t;   // covers 1024*512
        {
            int n = id >> 9, k = id & 511;
            float wv = (n < Hn) ? W_B[k * Hn + n] : W_C[k * Hn + (n - Hn)];
            WbcT[id] = __float2bfloat16(wv);   // WbcT[n][k] = W[k][n]
        }
        if (id < Hn * Hn) {
            int n = id >> 9, k = id & 511;
            WoT[id] = __float2bfloat16(W_out[k * Hn + n]);
        }
        if (id < 2 * Hn) bbc[id] = (id < Hn) ? b_B[id] : b_C[id - Hn];
        return;
    }
    // LN role: one row per wave, no LDS, shfl_xor butterfly
    int wid = t >> 6, lane = t & 63;
    int blk = blockIdx.x;
    int row = (blk & 7) * Ln + (blk >> 3) * 4 + wid;   // XCD-aligned: blk%8 = batch
    const float4* xr = reinterpret_cast<const float4*>(x + (size_t)row * Dn);
    float4 pa = xr[lane], pb = xr[lane + 64];
    float s  = pa.x + pa.y + pa.z + pa.w + pb.x + pb.y + pb.z + pb.w;
    float s2 = pa.x * pa.x + pa.y * pa.y + pa.z * pa.z + pa.w * pa.w
             + pb.x * pb.x + pb.y * pb.y + pb.z * pb.z + pb.w * pb.w;
    #pragma unroll
    for (int off = 1; off < 64; off <<= 1) {
        s  += __shfl_xor(s, off);
        s2 += __shfl_xor(s2, off);
    }
    float mu = s * (1.0f / Dn);
    float var = s2 * (1.0f / Dn) - mu * mu;
    float inv = rsqrtf(var + 1e-5f);
    const float4* g4 = reinterpret_cast<const float4*>(gamma);
    const float4* b4 = reinterpret_cast<const float4*>(beta);
    float4 ga = g4[lane], gb = g4[lane + 64];
    float4 ba = b4[lane], bb = b4[lane + 64];
    __hip_bfloat16 o[8];
    o[0] = __float2bfloat16((pa.x - mu) * inv * ga.x + ba.x);
    o[1] = __float2bfloat16((pa.y - mu) * inv * ga.y + ba.y);
    o[2] = __float2bfloat16((pa.z - mu) * inv * ga.z + ba.z);
    o[3] = __float2bfloat16((pa.w - mu) * inv * ga.w + ba.w);
    o[4] = __float2bfloat16((pb.x - mu) * inv * gb.x + bb.x);
    o[5] = __float2bfloat16((pb.y - mu) * inv * gb.y + bb.y);
    o[6] = __float2bfloat16((pb.z - mu) * inv * gb.z + bb.z);
    o[7] = __float2bfloat16((pb.w - mu) * inv * gb.w + bb.w);
    ushort4* xo = reinterpret_cast<ushort4*>(xn + (size_t)row * Dn);
    xo[lane]      = *reinterpret_cast<ushort4*>(&o[0]);
    xo[lane + 64] = *reinterpret_cast<ushort4*>(&o[4]);
}

// ---------------------------------------------------------------- 8-phase 128^2 GEMM
// C[M][NT] = A[M][512] * BT[NT][512]^T + bias.  BM=BN=128, BK=64, 4 waves,
// dbuf LDS 64KB -> 2 blocks/CU.  XOR swizzle slot^=(row&7) both sides.
// WRITE_S: lean fused chunk-sum  S[c,h] = sum_r v_r * a_h^(63-r)
template <int NT, bool OUT_BF16, bool WRITE_S>
__global__ __launch_bounds__(256, 2) void gemm4_kernel(
    const __hip_bfloat16* __restrict__ A,
    const __hip_bfloat16* __restrict__ BT,
    const float* __restrict__ bias,
    void* __restrict__ Cout,
    const float* __restrict__ Av, float* __restrict__ Sout)
{
    constexpr int K = 512, NIT = 4;            // 8 K-tiles of 64, 2 per iter
    extern __shared__ unsigned short lds[];    // 32768 shorts = 64 KB

    int nwg = gridDim.x, bid = blockIdx.x;
    int bswz = (bid & 7) * (nwg >> 3) + (bid >> 3);   // XCD swizzle (nwg%8==0)
    constexpr int NBN = NT / 128;
    int bm = bswz / NBN, bnb = bswz % NBN;
    int row0 = bm * 128, col0 = bnb * 128;

    int tid = threadIdx.x;
    int w = tid >> 6, l = tid & 63;
    int rl = l & 15, qg = l >> 4;

    // staging: lane -> row (l>>3), slot (l&7); pre-swizzled global col
    int scol = ((l & 7) ^ (l >> 3)) * 8;
    const __hip_bfloat16* gA = A  + (size_t)(row0 + w * 16 + (l >> 3)) * K + scol;
    const __hip_bfloat16* gB = BT + (size_t)(col0 + w * 16 + (l >> 3)) * K + scol;

    // LDS shorts: buf*16384 | A:0 B:8192 | half*4096 | row*64 | slot*8
#define GLDS(src, dst) __builtin_amdgcn_global_load_lds( \
        (const __attribute__((address_space(1))) void*)(const void*)(src), \
        (__attribute__((address_space(3))) void*)(void*)(dst), 16, 0, 0)
#define STA(b, kt, h, sub) GLDS(gA + (size_t)((h) * 64 + (sub) * 8) * K + (kt) * 64, \
        &lds[(b) * 16384 + (h) * 4096 + w * 1024 + (sub) * 512])
#define STB(b, kt, h, sub) GLDS(gB + (size_t)((h) * 64 + (sub) * 8) * K + (kt) * 64, \
        &lds[(b) * 16384 + 8192 + (h) * 4096 + w * 1024 + (sub) * 512])
#define STAGE_AU(b, kt, h) { STA(b, kt, h, 0); STA(b, kt, h, 1); }
#define STAGE_BU(b, kt, h) { STB(b, kt, h, 0); STB(b, kt, h, 1); }
#define BARRIER { asm volatile("" ::: "memory"); __builtin_amdgcn_s_barrier(); \
                  asm volatile("" ::: "memory"); }
#define VMCNT(n) asm volatile("s_waitcnt vmcnt(" #n ")" ::: "memory")

    int aoff = ((w >> 1) * 64 + rl) * 64;
    int boff = 8192 + ((w & 1) * 64 + rl) * 64;
    int s0k0 = (qg ^ (rl & 7)) * 8;            // kk=0 slot byte-pairs
    int s0k1 = ((4 + qg) ^ (rl & 7)) * 8;      // kk=1

    f32x4 acc[4][4] = {};
    bf16x8 af[2][2], bfr[4][2];

#define RD_A(mq, b) { _Pragma("unroll") for (int i2 = 0; i2 < 2; ++i2) { \
        af[i2][0] = *(const bf16x8*)&lds[(b) * 16384 + aoff + ((mq) * 32 + i2 * 16) * 64 + s0k0]; \
        af[i2][1] = *(const bf16x8*)&lds[(b) * 16384 + aoff + ((mq) * 32 + i2 * 16) * 64 + s0k1]; } }
#define RD_B(nq, b) { _Pragma("unroll") for (int j2 = 0; j2 < 2; ++j2) { \
        bfr[(nq) * 2 + j2][0] = *(const bf16x8*)&lds[(b) * 16384 + boff + ((nq) * 32 + j2 * 16) * 64 + s0k0]; \
        bfr[(nq) * 2 + j2][1] = *(const bf16x8*)&lds[(b) * 16384 + boff + ((nq) * 32 + j2 * 16) * 64 + s0k1]; } }
#define MM(mq, nq) { __builtin_amdgcn_s_setprio(1); \
        _Pragma("unroll") for (int i2 = 0; i2 < 2; ++i2) \
        _Pragma("unroll") for (int j2 = 0; j2 < 2; ++j2) \
        _Pragma("unroll") for (int kk = 0; kk < 2; ++kk) \
            acc[(mq) * 2 + i2][(nq) * 2 + j2] = __builtin_amdgcn_mfma_f32_16x16x32_bf16( \
                af[i2][kk], bfr[(nq) * 2 + j2][kk], acc[(mq) * 2 + i2][(nq) * 2 + j2], 0, 0, 0); \
        __builtin_amdgcn_s_setprio(0); }

    // prologue: kt0 complete into b0, kt1 B-halves into b1 (A jit at ph1/2)
    STAGE_BU(0, 0, 0); STAGE_BU(0, 0, 1); STAGE_AU(0, 0, 0); STAGE_AU(0, 0, 1);
    STAGE_BU(1, 1, 0); STAGE_BU(1, 1, 1);
    VMCNT(4);          // kt0's 8 loads landed; kt1's 4 B-loads in flight
    BARRIER;

    for (int it = 0; it < NIT; ++it) {
        int e = 2 * it;
        bool more = (it < NIT - 1);
        // ph1  Q(0,0) on b0 (kt e)     | stage A.h0(b1, kt e+1)
        RD_A(0, 0); RD_B(0, 0);
        STAGE_AU(1, e + 1, 0);
        BARRIER; MM(0, 0); BARRIER;
        // ph2  Q(0,1)                  | stage A.h1(b1, kt e+1)
        RD_B(1, 0);
        STAGE_AU(1, e + 1, 1);
        BARRIER; MM(0, 1); BARRIER;
        // ph3  Q(1,1)                  | stage B.h0(b0, kt e+2)
        RD_A(1, 0);
        if (more) STAGE_BU(0, e + 2, 0);
        BARRIER; MM(1, 1); BARRIER;
        // ph4  Q(1,0)                  | stage B.h1(b0, kt e+2); gate for b1
        if (more) STAGE_BU(0, e + 2, 1);
        BARRIER; MM(1, 0);
        if (more) { VMCNT(4); } else { VMCNT(0); }
        BARRIER;
        // ph5  Q(0,0) on b1 (kt e+1)   | stage A.h0(b0, kt e+2)
        RD_A(0, 1); RD_B(0, 1);
        if (more) STAGE_AU(0, e + 2, 0);
        BARRIER; MM(0, 0); BARRIER;
        // ph6  Q(0,1)                  | stage A.h1(b0, kt e+2)
        RD_B(1, 1);
        if (more) STAGE_AU(0, e + 2, 1);
        BARRIER; MM(0, 1); BARRIER;
        // ph7  Q(1,1)                  | stage B.h0(b1, kt e+3)
        RD_A(1, 1);
        if (more) STAGE_BU(1, e + 3, 0);
        BARRIER; MM(1, 1); BARRIER;
        // ph8  Q(1,0)                  | stage B.h1(b1, kt e+3); gate for b0
        if (more) {
            STAGE_BU(1, e + 3, 1);
            BARRIER; MM(1, 0); VMCNT(4); BARRIER;
        } else {
            BARRIER; MM(1, 0);
        }
    }

    // epilogue: C = acc + bias; lean fused chunk-sum S
    int crow0 = row0 + (w >> 1) * 64 + qg * 4;
    int ccol0 = col0 + (w & 1) * 64 + rl;
    int cg = (row0 + (w >> 1) * 64) >> 6;      // global chunk id (b*64+c)
    float aCol[4];
    if (WRITE_S && col0 < 512) {
        #pragma unroll
        for (int n = 0; n < 4; ++n) aCol[n] = Av[ccol0 + n * 16];  // hoisted, overlapped
    }
    #pragma unroll
    for (int n = 0; n < 4; ++n) {
        int col = ccol0 + n * 16;
        float bv = bias[col];
        float v[4][4];
        #pragma unroll
        for (int i = 0; i < 4; ++i) {
            #pragma unroll
            for (int j = 0; j < 4; ++j) {
                v[i][j] = acc[i][n][j] + bv;
                size_t idx = (size_t)(crow0 + i * 16 + j) * NT + col;
                if (OUT_BF16)
                    ((__hip_bfloat16*)Cout)[idx] = __float2bfloat16(v[i][j]);
                else
                    ((float*)Cout)[idx] = v[i][j];
            }
        }
        if (WRITE_S && col0 < 512) {
            float a = aCol[n];
            float a2 = a * a, a4 = a2 * a2, a8 = a4 * a4, a16 = a8 * a8;
            float s = 0.f;
            #pragma unroll
            for (int i = 0; i < 4; ++i) {
                float u = ((v[i][0] * a + v[i][1]) * a + v[i][2]) * a + v[i][3];
                s = s * a16 + u;                // same assoc order as R5 (verified)
            }
            float aq = (qg == 0) ? a8 * a4 : (qg == 1) ? a8 : (qg == 2) ? a4 : 1.0f;
            s *= aq;                            // s = sum_r v_r a^(63-r), partial over qg
            s += __shfl_xor(s, 16);
            s += __shfl_xor(s, 32);
            if (qg == 0) Sout[(size_t)cg * Hn + col] = s;
        }
    }
#undef GLDS
#undef STA
#undef STB
#undef STAGE_AU
#undef STAGE_BU
#undef BARRIER
#undef VMCNT
#undef RD_A
#undef RD_B
#undef MM
}

// ---------------------------------------------------------------- fused scan (carry + local scan + readout)
// BC layout: [row][1024] bf16, Bt = cols 0..511, Ct = cols 512..1023
// Block index XCD-aligned: blk%8 = batch, matching GEMM1 (producer of BC/S)
// and GEMM2 (consumer of Y): XCD b owns batch b end-to-end.
__global__ __launch_bounds__(256) void scan_kernel(
    const __hip_bfloat16* __restrict__ BC, const float* __restrict__ Av,
    const float* __restrict__ S, __hip_bfloat16* __restrict__ Y)
{
    int blk = blockIdx.x;                       // 1024 = c*16 + half*8 + b
    int b = blk & 7;
    int half = (blk >> 3) & 1;
    int c = blk >> 4;
    int hh = half * 256 + threadIdx.x;
    float a = Av[hh];
    float aG = a;
    #pragma unroll
    for (int i = 0; i < 6; ++i) aG *= aG;       // a^64
    // carry: h entering chunk c = Horner over S[b, 0..c-1, hh]
    float h = 0.f;
    const float* Sp = S + (size_t)b * NCHUNK * Hn + hh;
    for (int cc = 0; cc < c; ++cc)
        h = aG * h + Sp[(size_t)cc * Hn];
    // local scan + readout
    const __hip_bfloat16* p = BC + ((size_t)(b * Ln + c * CHUNK) * 1024) + hh;
    __hip_bfloat16* yp = Y + ((size_t)(b * Ln + c * CHUNK) * Hn) + hh;
    #pragma unroll 8
    for (int i = 0; i < CHUNK; ++i) {
        float bv = __bfloat162float(p[(size_t)i * 1024]);
        float cv = __bfloat162float(p[(size_t)i * 1024 + 512]);
        h = a * h + bv;
        yp[(size_t)i * Hn] = __float2bfloat16(cv * h);
    }
}

// ---------------------------------------------------------------- launch
extern "C" void kernel_launch(void* const* d_in, const int* in_sizes, int n_in,
                              void* d_out, int out_size, void* d_ws, size_t ws_size,
                              hipStream_t stream)
{
    const float* x     = (const float*)d_in[0];
    const float* ln_g  = (const float*)d_in[1];
    const float* ln_b  = (const float*)d_in[2];
    const float* W_B   = (const float*)d_in[3];
    const float* b_B   = (const float*)d_in[4];
    const float* W_C   = (const float*)d_in[5];
    const float* b_C   = (const float*)d_in[6];
    const float* W_out = (const float*)d_in[7];
    const float* b_out = (const float*)d_in[8];
    const float* Avec  = (const float*)d_in[9];

    char* ws = (char*)d_ws;
    __hip_bfloat16* WbcT = (__hip_bfloat16*)(ws);                        // 1 MB
    __hip_bfloat16* WoT  = (__hip_bfloat16*)(ws + (1u << 20));           // 0.5 MB
    float*          bbc  = (float*)(ws + (1u << 20) + (1u << 19));       // 4 KB
    __hip_bfloat16* XN   = (__hip_bfloat16*)(ws + (2u << 20));           // 32 MB
    __hip_bfloat16* BC   = (__hip_bfloat16*)(ws + (34u << 20));          // 64 MB
    float*          Sbuf = (float*)(ws + (98u << 20));                   // 1 MB
    __hip_bfloat16* Y    = (__hip_bfloat16*)(ws + (100u << 20));         // 32 MB

    hipFuncSetAttribute((const void*)gemm4_kernel<1024, true, true>,
                        hipFuncAttributeMaxDynamicSharedMemorySize, 65536);
    hipFuncSetAttribute((const void*)gemm4_kernel<512, false, false>,
                        hipFuncAttributeMaxDynamicSharedMemorySize, 65536);

    pre_kernel<<<LNBLK + 2048, 256, 0, stream>>>(
        x, ln_g, ln_b, W_B, W_C, W_out, b_B, b_C, XN, WbcT, WoT, bbc);
    gemm4_kernel<1024, true, true><<<(Mrows / 128) * (1024 / 128), 256, 65536, stream>>>(
        XN, WbcT, bbc, BC, Avec, Sbuf);
    scan_kernel<<<Bn * NCHUNK * 2, 256, 0, stream>>>(BC, Avec, Sbuf, Y);
    gemm4_kernel<512, false, false><<<(Mrows / 128) * (512 / 128), 256, 65536, stream>>>(
        Y, WoT, b_out, d_out, nullptr, nullptr);
}

// Round 8
// 121.575 us; speedup vs baseline: 1.0310x; 1.0310x over previous
//
#include <hip/hip_runtime.h>
#include <hip/hip_bf16.h>
#include <stdint.h>

typedef __bf16 bf16x8 __attribute__((ext_vector_type(8)));
typedef float f32x4 __attribute__((ext_vector_type(4)));

constexpr int Bn = 8, Ln = 4096, Dn = 512, Hn = 512;
constexpr int Mrows = Bn * Ln;                  // 32768
constexpr int CHUNK = 64, NCHUNK = Ln / CHUNK;  // 64 chunks of 64
constexpr int LNBLK = Mrows / 4;                // 8192: 1 row per wave, 4 waves/block

// ---------------------------------------------------------------- pre: LN (wave-per-row) + weight prep
__global__ __launch_bounds__(256) void pre_kernel(
    const float* __restrict__ x, const float* __restrict__ gamma,
    const float* __restrict__ beta,
    const float* __restrict__ W_B, const float* __restrict__ W_C,
    const float* __restrict__ W_out, const float* __restrict__ b_B,
    const float* __restrict__ b_C,
    __hip_bfloat16* __restrict__ xn,
    __hip_bfloat16* __restrict__ WbcT, __hip_bfloat16* __restrict__ WoT,
    float* __restrict__ bbc)
{
    int t = threadIdx.x;
    if (blockIdx.x >= LNBLK) {                 // prep role: 2048 blocks
        int id = (blockIdx.x - LNBLK) * 256 + t;   // covers 1024*512
        {
            int n = id >> 9, k = id & 511;
            float wv = (n < Hn) ? W_B[k * Hn + n] : W_C[k * Hn + (n - Hn)];
            WbcT[id] = __float2bfloat16(wv);   // WbcT[n][k] = W[k][n]
        }
        if (id < Hn * Hn) {
            int n = id >> 9, k = id & 511;
            WoT[id] = __float2bfloat16(W_out[k * Hn + n]);
        }
        if (id < 2 * Hn) bbc[id] = (id < Hn) ? b_B[id] : b_C[id - Hn];
        return;
    }
    // LN role: one row per wave, no LDS, shfl_xor butterfly
    int wid = t >> 6, lane = t & 63;
    int blk = blockIdx.x;
    int row = (blk & 7) * Ln + (blk >> 3) * 4 + wid;   // XCD-aligned: blk%8 = batch
    const float4* xr = reinterpret_cast<const float4*>(x + (size_t)row * Dn);
    float4 pa = xr[lane], pb = xr[lane + 64];
    float s  = pa.x + pa.y + pa.z + pa.w + pb.x + pb.y + pb.z + pb.w;
    float s2 = pa.x * pa.x + pa.y * pa.y + pa.z * pa.z + pa.w * pa.w
             + pb.x * pb.x + pb.y * pb.y + pb.z * pb.z + pb.w * pb.w;
    #pragma unroll
    for (int off = 1; off < 64; off <<= 1) {
        s  += __shfl_xor(s, off);
        s2 += __shfl_xor(s2, off);
    }
    float mu = s * (1.0f / Dn);
    float var = s2 * (1.0f / Dn) - mu * mu;
    float inv = rsqrtf(var + 1e-5f);
    const float4* g4 = reinterpret_cast<const float4*>(gamma);
    const float4* b4 = reinterpret_cast<const float4*>(beta);
    float4 ga = g4[lane], gb = g4[lane + 64];
    float4 ba = b4[lane], bb = b4[lane + 64];
    __hip_bfloat16 o[8];
    o[0] = __float2bfloat16((pa.x - mu) * inv * ga.x + ba.x);
    o[1] = __float2bfloat16((pa.y - mu) * inv * ga.y + ba.y);
    o[2] = __float2bfloat16((pa.z - mu) * inv * ga.z + ba.z);
    o[3] = __float2bfloat16((pa.w - mu) * inv * ga.w + ba.w);
    o[4] = __float2bfloat16((pb.x - mu) * inv * gb.x + bb.x);
    o[5] = __float2bfloat16((pb.y - mu) * inv * gb.y + bb.y);
    o[6] = __float2bfloat16((pb.z - mu) * inv * gb.z + bb.z);
    o[7] = __float2bfloat16((pb.w - mu) * inv * gb.w + bb.w);
    ushort4* xo = reinterpret_cast<ushort4*>(xn + (size_t)row * Dn);
    xo[lane]      = *reinterpret_cast<ushort4*>(&o[0]);
    xo[lane + 64] = *reinterpret_cast<ushort4*>(&o[4]);
}

// ---------------------------------------------------------------- 4-phase 128^2 GEMM
// C[M][NT] = A[M][512] * BT[NT][512]^T + bias.  BM=BN=128, BK=64, 4 waves,
// dbuf LDS 64KB -> 2 blocks/CU.  XOR swizzle slot^=(row&7) both sides.
// 4 phases per iteration (2 K-tiles), 16 MFMA per phase (halved barrier count
// vs the 8-phase R4-R7 loop). Staging ledger (region: last read -> stage slot):
//   buf0.B: P1 -> P2 | buf0.A: P2 -> P3 | buf1.B: P3 -> P4 | buf1.A: prevP4 -> P1(JIT)
// Gates: end-P2 VMCNT(4) [buf1.A landed], end-P4 VMCNT(4) [buf0 landed].
template <int NT, bool OUT_BF16, bool WRITE_S>
__global__ __launch_bounds__(256, 2) void gemm4_kernel(
    const __hip_bfloat16* __restrict__ A,
    const __hip_bfloat16* __restrict__ BT,
    const float* __restrict__ bias,
    void* __restrict__ Cout,
    const float* __restrict__ Av, float* __restrict__ Sout)
{
    constexpr int K = 512, NIT = 4;            // 8 K-tiles of 64, 2 per iter
    extern __shared__ unsigned short lds[];    // 32768 shorts = 64 KB

    int nwg = gridDim.x, bid = blockIdx.x;
    int bswz = (bid & 7) * (nwg >> 3) + (bid >> 3);   // XCD swizzle (nwg%8==0)
    constexpr int NBN = NT / 128;
    int bm = bswz / NBN, bnb = bswz % NBN;
    int row0 = bm * 128, col0 = bnb * 128;

    int tid = threadIdx.x;
    int w = tid >> 6, l = tid & 63;
    int rl = l & 15, qg = l >> 4;

    // staging: lane -> row (l>>3), slot (l&7); pre-swizzled global col
    int scol = ((l & 7) ^ (l >> 3)) * 8;
    const __hip_bfloat16* gA = A  + (size_t)(row0 + w * 16 + (l >> 3)) * K + scol;
    const __hip_bfloat16* gB = BT + (size_t)(col0 + w * 16 + (l >> 3)) * K + scol;

    // LDS shorts: buf*16384 | A:0 B:8192 | half*4096 | row*64 | slot*8
#define GLDS(src, dst) __builtin_amdgcn_global_load_lds( \
        (const __attribute__((address_space(1))) void*)(const void*)(src), \
        (__attribute__((address_space(3))) void*)(void*)(dst), 16, 0, 0)
#define STA(b, kt, h, sub) GLDS(gA + (size_t)((h) * 64 + (sub) * 8) * K + (kt) * 64, \
        &lds[(b) * 16384 + (h) * 4096 + w * 1024 + (sub) * 512])
#define STB(b, kt, h, sub) GLDS(gB + (size_t)((h) * 64 + (sub) * 8) * K + (kt) * 64, \
        &lds[(b) * 16384 + 8192 + (h) * 4096 + w * 1024 + (sub) * 512])
#define STAGE_AU(b, kt, h) { STA(b, kt, h, 0); STA(b, kt, h, 1); }
#define STAGE_BU(b, kt, h) { STB(b, kt, h, 0); STB(b, kt, h, 1); }
#define BARRIER { asm volatile("" ::: "memory"); __builtin_amdgcn_s_barrier(); \
                  asm volatile("" ::: "memory"); }
#define VMCNT(n) asm volatile("s_waitcnt vmcnt(" #n ")" ::: "memory")

    int aoff = ((w >> 1) * 64 + rl) * 64;
    int boff = 8192 + ((w & 1) * 64 + rl) * 64;
    int s0k0 = (qg ^ (rl & 7)) * 8;            // kk=0 slot byte-pairs
    int s0k1 = ((4 + qg) ^ (rl & 7)) * 8;      // kk=1

    f32x4 acc[4][4] = {};
    bf16x8 af[2][2], bfr[4][2];

#define RD_A(mq, b) { _Pragma("unroll") for (int i2 = 0; i2 < 2; ++i2) { \
        af[i2][0] = *(const bf16x8*)&lds[(b) * 16384 + aoff + ((mq) * 32 + i2 * 16) * 64 + s0k0]; \
        af[i2][1] = *(const bf16x8*)&lds[(b) * 16384 + aoff + ((mq) * 32 + i2 * 16) * 64 + s0k1]; } }
#define RD_B(nq, b) { _Pragma("unroll") for (int j2 = 0; j2 < 2; ++j2) { \
        bfr[(nq) * 2 + j2][0] = *(const bf16x8*)&lds[(b) * 16384 + boff + ((nq) * 32 + j2 * 16) * 64 + s0k0]; \
        bfr[(nq) * 2 + j2][1] = *(const bf16x8*)&lds[(b) * 16384 + boff + ((nq) * 32 + j2 * 16) * 64 + s0k1]; } }
// 16-MFMA cluster: both N-quadrants of M-half mq. Per-acc visit order
// (kk0 then kk1, one visit per kt) identical to the 8-phase loop.
#define MM2(mq) { __builtin_amdgcn_s_setprio(1); \
        _Pragma("unroll") for (int nq = 0; nq < 2; ++nq) \
        _Pragma("unroll") for (int i2 = 0; i2 < 2; ++i2) \
        _Pragma("unroll") for (int j2 = 0; j2 < 2; ++j2) \
        _Pragma("unroll") for (int kk = 0; kk < 2; ++kk) \
            acc[(mq) * 2 + i2][nq * 2 + j2] = __builtin_amdgcn_mfma_f32_16x16x32_bf16( \
                af[i2][kk], bfr[nq * 2 + j2][kk], acc[(mq) * 2 + i2][nq * 2 + j2], 0, 0, 0); \
        __builtin_amdgcn_s_setprio(0); }

    // prologue: kt0 complete into b0, kt1 B-halves into b1 (A JIT at P1)
    STAGE_BU(0, 0, 0); STAGE_BU(0, 0, 1); STAGE_AU(0, 0, 0); STAGE_AU(0, 0, 1);
    STAGE_BU(1, 1, 0); STAGE_BU(1, 1, 1);
    VMCNT(4);          // kt0's 8 loads landed; kt1's 4 B-loads in flight
    BARRIER;

    for (int it = 0; it < NIT; ++it) {
        int e = 2 * it;
        bool more = (it < NIT - 1);
        // P1: buf0 all-B + A-half reads; MFMA Q(0,*) | JIT stage buf1.A (kt e+1)
        RD_A(0, 0); RD_B(0, 0); RD_B(1, 0);
        STAGE_AU(1, e + 1, 0); STAGE_AU(1, e + 1, 1);
        BARRIER; MM2(0); BARRIER;
        // P2: MFMA Q(1,*) on buf0 | stage buf0.B (kt e+2); gate buf1.A landed
        RD_A(1, 0);
        if (more) { STAGE_BU(0, e + 2, 0); STAGE_BU(0, e + 2, 1); }
        BARRIER; MM2(1);
        if (more) { VMCNT(4); } else { VMCNT(0); }
        BARRIER;
        // P3: buf1 reads; MFMA Q(0,*) | stage buf0.A (kt e+2)
        RD_A(0, 1); RD_B(0, 1); RD_B(1, 1);
        if (more) { STAGE_AU(0, e + 2, 0); STAGE_AU(0, e + 2, 1); }
        BARRIER; MM2(0); BARRIER;
        // P4: MFMA Q(1,*) on buf1 | stage buf1.B (kt e+3); gate buf0 landed
        RD_A(1, 1);
        if (more) { STAGE_BU(1, e + 3, 0); STAGE_BU(1, e + 3, 1); }
        BARRIER; MM2(1);
        if (more) { VMCNT(4); BARRIER; }
    }

    // epilogue: C = acc + bias; lean fused chunk-sum S
    int crow0 = row0 + (w >> 1) * 64 + qg * 4;
    int ccol0 = col0 + (w & 1) * 64 + rl;
    int cg = (row0 + (w >> 1) * 64) >> 6;      // global chunk id (b*64+c)
    float aCol[4];
    if (WRITE_S && col0 < 512) {
        #pragma unroll
        for (int n = 0; n < 4; ++n) aCol[n] = Av[ccol0 + n * 16];  // hoisted
    }
    #pragma unroll
    for (int n = 0; n < 4; ++n) {
        int col = ccol0 + n * 16;
        float bv = bias[col];
        float v[4][4];
        #pragma unroll
        for (int i = 0; i < 4; ++i) {
            #pragma unroll
            for (int j = 0; j < 4; ++j) {
                v[i][j] = acc[i][n][j] + bv;
                size_t idx = (size_t)(crow0 + i * 16 + j) * NT + col;
                if (OUT_BF16)
                    ((__hip_bfloat16*)Cout)[idx] = __float2bfloat16(v[i][j]);
                else
                    ((float*)Cout)[idx] = v[i][j];
            }
        }
        if (WRITE_S && col0 < 512) {
            float a = aCol[n];
            float a2 = a * a, a4 = a2 * a2, a8 = a4 * a4, a16 = a8 * a8;
            float s = 0.f;
            #pragma unroll
            for (int i = 0; i < 4; ++i) {
                float u = ((v[i][0] * a + v[i][1]) * a + v[i][2]) * a + v[i][3];
                s = s * a16 + u;
            }
            float aq = (qg == 0) ? a8 * a4 : (qg == 1) ? a8 : (qg == 2) ? a4 : 1.0f;
            s *= aq;                            // s = sum_r v_r a^(63-r), partial over qg
            s += __shfl_xor(s, 16);
            s += __shfl_xor(s, 32);
            if (qg == 0) Sout[(size_t)cg * Hn + col] = s;
        }
    }
#undef GLDS
#undef STA
#undef STB
#undef STAGE_AU
#undef STAGE_BU
#undef BARRIER
#undef VMCNT
#undef RD_A
#undef RD_B
#undef MM2
}

// ---------------------------------------------------------------- fused scan (carry + local scan + readout)
// BC layout: [row][1024] bf16, Bt = cols 0..511, Ct = cols 512..1023
__global__ __launch_bounds__(256) void scan_kernel(
    const __hip_bfloat16* __restrict__ BC, const float* __restrict__ Av,
    const float* __restrict__ S, __hip_bfloat16* __restrict__ Y)
{
    int blk = blockIdx.x;                       // 1024 = c*16 + half*8 + b
    int b = blk & 7;
    int half = (blk >> 3) & 1;
    int c = blk >> 4;
    int hh = half * 256 + threadIdx.x;
    float a = Av[hh];
    float aG = a;
    #pragma unroll
    for (int i = 0; i < 6; ++i) aG *= aG;       // a^64
    // carry: h entering chunk c = Horner over S[b, 0..c-1, hh]
    float h = 0.f;
    const float* Sp = S + (size_t)b * NCHUNK * Hn + hh;
    for (int cc = 0; cc < c; ++cc)
        h = aG * h + Sp[(size_t)cc * Hn];
    // local scan + readout
    const __hip_bfloat16* p = BC + ((size_t)(b * Ln + c * CHUNK) * 1024) + hh;
    __hip_bfloat16* yp = Y + ((size_t)(b * Ln + c * CHUNK) * Hn) + hh;
    #pragma unroll 8
    for (int i = 0; i < CHUNK; ++i) {
        float bv = __bfloat162float(p[(size_t)i * 1024]);
        float cv = __bfloat162float(p[(size_t)i * 1024 + 512]);
        h = a * h + bv;
        yp[(size_t)i * Hn] = __float2bfloat16(cv * h);
    }
}

// ---------------------------------------------------------------- launch
extern "C" void kernel_launch(void* const* d_in, const int* in_sizes, int n_in,
                              void* d_out, int out_size, void* d_ws, size_t ws_size,
                              hipStream_t stream)
{
    const float* x     = (const float*)d_in[0];
    const float* ln_g  = (const float*)d_in[1];
    const float* ln_b  = (const float*)d_in[2];
    const float* W_B   = (const float*)d_in[3];
    const float* b_B   = (const float*)d_in[4];
    const float* W_C   = (const float*)d_in[5];
    const float* b_C   = (const float*)d_in[6];
    const float* W_out = (const float*)d_in[7];
    const float* b_out = (const float*)d_in[8];
    const float* Avec  = (const float*)d_in[9];

    char* ws = (char*)d_ws;
    __hip_bfloat16* WbcT = (__hip_bfloat16*)(ws);                        // 1 MB
    __hip_bfloat16* WoT  = (__hip_bfloat16*)(ws + (1u << 20));           // 0.5 MB
    float*          bbc  = (float*)(ws + (1u << 20) + (1u << 19));       // 4 KB
    __hip_bfloat16* XN   = (__hip_bfloat16*)(ws + (2u << 20));           // 32 MB
    __hip_bfloat16* BC   = (__hip_bfloat16*)(ws + (34u << 20));          // 64 MB
    float*          Sbuf = (float*)(ws + (98u << 20));                   // 1 MB
    __hip_bfloat16* Y    = (__hip_bfloat16*)(ws + (100u << 20));         // 32 MB

    hipFuncSetAttribute((const void*)gemm4_kernel<1024, true, true>,
                        hipFuncAttributeMaxDynamicSharedMemorySize, 65536);
    hipFuncSetAttribute((const void*)gemm4_kernel<512, false, false>,
                        hipFuncAttributeMaxDynamicSharedMemorySize, 65536);

    pre_kernel<<<LNBLK + 2048, 256, 0, stream>>>(
        x, ln_g, ln_b, W_B, W_C, W_out, b_B, b_C, XN, WbcT, WoT, bbc);
    gemm4_kernel<1024, true, true><<<(Mrows / 128) * (1024 / 128), 256, 65536, stream>>>(
        XN, WbcT, bbc, BC, Avec, Sbuf);
    scan_kernel<<<Bn * NCHUNK * 2, 256, 0, stream>>>(BC, Avec, Sbuf, Y);
    gemm4_kernel<512, false, false><<<(Mrows / 128) * (512 / 128), 256, 65536, stream>>>(
        Y, WoT, b_out, d_out, nullptr, nullptr);
}